// Round 6
// baseline (206.263 us; speedup 1.0000x reference)
//
#include <hip/hip_runtime.h>
#include <hip/hip_bf16.h>
#include <math.h>

// Problem constants
#define T_ 4
#define N_ 16
#define F_ 6
#define L_ 1024
#define A_ 21
#define K_ 20
#define U_ 256
#define LOUT 1005            // L - K + 1
#define NIMG 384             // T*N*F
#define SZ_S (T_*N_*U_)      // 16384
#define SZ_R (K_*A_*U_)      // 107520

// Packed-X geometry: row stride 24 shorts (48 B). For output row l, contraction
// slot c maps to tap=c/24, col=c%24 (independent of l) -> contiguous aligned
// K-window of 512 slots (16 MFMA K-steps of 32). Cols 21..23 and tap>=20 are
// zero on the R side.
#define XPR 24               // shorts per packed row
#define XROWS 1056           // padded rows per image
#define NSTEP 16             // K-steps of 32 slots (512 >= 19*24+20+1)
#define RT_SHORTS (NSTEP * U_ * 32)   // 131072 shorts = 256 KB

typedef __attribute__((ext_vector_type(8))) short short8;   // 8 bf16 (4 VGPR)
typedef __attribute__((ext_vector_type(4))) float f32x4;    // 4 f32 acc

__device__ __forceinline__ unsigned short f2bf(float f) {
  unsigned int u = __float_as_uint(f);
  u += 0x7FFFu + ((u >> 16) & 1u);   // round to nearest even
  return (unsigned short)(u >> 16);
}

__device__ __forceinline__ void atomicMaxF(float* addr, float val) {
  if (val >= 0.f) atomicMax((int*)addr, __float_as_int(val));
  else            atomicMin((unsigned int*)addr, __float_as_uint(val));
}

// Async global->LDS, 16B per lane. LDS dest is wave-uniform base + lane*16.
__device__ __forceinline__ void gload_lds16(const void* g, void* l) {
  __builtin_amdgcn_global_load_lds(
      (const __attribute__((address_space(1))) void*)g,
      (__attribute__((address_space(3))) void*)l, 16, 0, 0);
}

// S init to -inf, R (fp32, exact) into d_out, and Rt = bf16 R scattered into
// slot order: Rt[(s>>5)*8192 + u*32 + (s&31)], s = k*24 + a. Pad slots are
// zeroed beforehand by hipMemsetAsync.
__global__ void prep_kernel(const float* __restrict__ P_logit,
                            const float* __restrict__ Q,
                            float* __restrict__ out,
                            unsigned short* __restrict__ Rt) {
  int tid = blockIdx.x * blockDim.x + threadIdx.x;
  if (tid < SZ_S) out[tid] = -INFINITY;
  if (tid >= K_ * U_) return;
  int k = tid / U_;
  int u = tid - k * U_;
  const float* pl = P_logit + (size_t)k * A_ * U_ + u;
  float v[A_];
  float m = -INFINITY;
#pragma unroll
  for (int a = 0; a < A_; ++a) { v[a] = pl[(size_t)a * U_]; m = fmaxf(m, v[a]); }
  float s = 0.f;
#pragma unroll
  for (int a = 0; a < A_; ++a) { v[a] = expf(v[a] - m); s += v[a]; }
  float qs = 0.f;
#pragma unroll
  for (int a = 0; a < A_; ++a) qs += Q[a];
  float eps = qs * (1.0f / A_);
  float invs = 1.f / s;
  float* Rout = out + SZ_S;
#pragma unroll
  for (int a = 0; a < A_; ++a) {
    float r = logf(fmaxf(v[a] * invs / Q[a], eps));
    Rout[(size_t)(k * A_ + a) * U_ + u] = r;
    int sl = k * XPR + a;
    Rt[(size_t)(sl >> 5) * (U_ * 32) + u * 32 + (sl & 31)] = f2bf(r);
  }
}

// X (fp32 [n][1024][21]) -> Xp (bf16 [n][1056][24], zero-padded both dims).
__global__ void xconv_kernel(const float* __restrict__ X,
                             unsigned int* __restrict__ Xp32) {
  int t = blockIdx.x * blockDim.x + threadIdx.x;
  if (t >= NIMG * XROWS * 12) return;
  int w  = t % 12;
  int rl = t / 12;                 // n*XROWS + row
  int row = rl % XROWS;
  int n   = rl / XROWS;
  int c0 = w * 2;
  float v0 = 0.f, v1 = 0.f;
  if (row < L_) {
    const float* xr = X + ((size_t)n * L_ + row) * A_;
    if (c0 < A_)     v0 = xr[c0];
    if (c0 + 1 < A_) v1 = xr[c0 + 1];
  }
  unsigned int o = (unsigned int)f2bf(v0) | ((unsigned int)f2bf(v1) << 16);
  Xp32[(size_t)rl * 12 + w] = o;
}

// Conv as one GEMM: M=u (A=R slots), N=l (B=packed-X window), K=512 (16 steps).
// - X window (8 KB) staged once via global_load_lds; ONE barrier total.
// - R fragments read directly from global (L2-resident 256 KB), pre-swizzled
//   to fragment order, 3-K-step-deep register rotation (full unroll, all
//   indices compile-time -> no scratch, SSA renaming handles WAR).
// Block tile: 128 l x 128 u, 4 waves (2x2), wave 64u x 64l.
__global__ __launch_bounds__(256, 3) void conv_kernel(
    const unsigned short* __restrict__ Xp,
    const unsigned short* __restrict__ Rt,
    float* __restrict__ out) {
  __shared__ unsigned short lds_x[4096];   // 8192 B: rows l0..l0+170 (need 149)

  const int n  = blockIdx.z;
  const int l0 = blockIdx.y * 128;
  const int u0 = blockIdx.x * 128;
  const int wid  = threadIdx.x >> 6;
  const int lane = threadIdx.x & 63;

  // Stage packed X rows [l0 .. ] : 8 x 1KB chunks (2 per wave).
  const char* xsrc = (const char*)Xp + ((size_t)n * XROWS + l0) * (XPR * 2);
#pragma unroll
  for (int r = 0; r < 2; ++r) {
    int c = wid * 2 + r;
    gload_lds16(xsrc + c * 1024 + lane * 16, (char*)lds_x + c * 1024);
  }
  asm volatile("s_waitcnt vmcnt(0)" ::: "memory");
  __syncthreads();

  const int wl = wid >> 1;
  const int wu = wid & 1;
  const int fl = lane & 15;            // frag row (A: u) / col (B: l)
  const int fj = lane >> 4;            // k sub-chunk (8 shorts each)

  f32x4 acc[4][4];                     // [ut][lt]
#pragma unroll
  for (int ut = 0; ut < 4; ++ut)
#pragma unroll
    for (int lt = 0; lt < 4; ++lt)
      acc[ut][lt] = (f32x4){0.f, 0.f, 0.f, 0.f};

  // R frag base: shorts. frag(step, ut) = rb + step*8192 + ut*512
  const unsigned short* rb =
      Rt + (size_t)(u0 + wu * 64 + fl) * 32 + (fj << 3);
  // X frag base: shorts in LDS. frag(step, lt) at xb + lt*(16*24) + step*32
  const unsigned short* xb = lds_x + (wl * 64 + fl) * XPR + (fj << 3);

  // 3-deep R prefetch window: compute step s while step s+3 loads.
  short8 rwin[3][4];
#pragma unroll
  for (int p = 0; p < 3; ++p)
#pragma unroll
    for (int ut = 0; ut < 4; ++ut)
      rwin[p][ut] = *(const short8*)(rb + (size_t)p * 8192 + ut * 512);

#pragma unroll
  for (int s = 0; s < NSTEP; ++s) {
    short8 xf[4], cur[4];
#pragma unroll
    for (int lt = 0; lt < 4; ++lt)
      xf[lt] = *(const short8*)(xb + lt * (16 * XPR) + s * 32);
#pragma unroll
    for (int ut = 0; ut < 4; ++ut) cur[ut] = rwin[s % 3][ut];
    if (s + 3 < NSTEP) {
#pragma unroll
      for (int ut = 0; ut < 4; ++ut)
        rwin[s % 3][ut] =
            *(const short8*)(rb + (size_t)(s + 3) * 8192 + ut * 512);
    }
#pragma unroll
    for (int ut = 0; ut < 4; ++ut)
#pragma unroll
      for (int lt = 0; lt < 4; ++lt)
        acc[ut][lt] = __builtin_amdgcn_mfma_f32_16x16x32_bf16(
            cur[ut], xf[lt], acc[ut][lt], 0, 0, 0);
  }

  // Epilogue: D layout col(l)=lane&15, row(u)=(lane>>4)*4+reg -> lane holds
  // 4 consecutive u at fixed l => float4 store into row-major Z[l][u].
  float* Z = out + SZ_S + SZ_R;
  const int ug = fj << 2;
  float pmax[4][4];
#pragma unroll
  for (int ut = 0; ut < 4; ++ut)
#pragma unroll
    for (int r = 0; r < 4; ++r) pmax[ut][r] = -INFINITY;

#pragma unroll
  for (int lt = 0; lt < 4; ++lt) {
    const int l = l0 + wl * 64 + lt * 16 + fl;
    if (l < LOUT) {
      float* zrow = Z + ((size_t)n * LOUT + l) * U_ + u0 + wu * 64 + ug;
#pragma unroll
      for (int ut = 0; ut < 4; ++ut) {
        f32x4 v = acc[ut][lt];
        *(f32x4*)(zrow + ut * 16) = v;
#pragma unroll
        for (int r = 0; r < 4; ++r) pmax[ut][r] = fmaxf(pmax[ut][r], v[r]);
      }
    }
  }

#pragma unroll
  for (int off = 1; off < 16; off <<= 1)
#pragma unroll
    for (int ut = 0; ut < 4; ++ut)
#pragma unroll
      for (int r = 0; r < 4; ++r)
        pmax[ut][r] = fmaxf(pmax[ut][r], __shfl_xor(pmax[ut][r], off));

  if (fl == 0) {
    const int tn = n / F_;
    float* Sp = out + (size_t)tn * U_ + u0 + wu * 64 + ug;
#pragma unroll
    for (int ut = 0; ut < 4; ++ut)
#pragma unroll
      for (int r = 0; r < 4; ++r)
        atomicMaxF(Sp + ut * 16 + r, pmax[ut][r]);
  }
}

extern "C" void kernel_launch(void* const* d_in, const int* in_sizes, int n_in,
                              void* d_out, int out_size, void* d_ws, size_t ws_size,
                              hipStream_t stream) {
  const float* X       = (const float*)d_in[0];
  const float* P_logit = (const float*)d_in[1];
  const float* Q       = (const float*)d_in[2];
  float* out = (float*)d_out;

  unsigned short* Rt = (unsigned short*)d_ws;            // 256 KB
  const size_t rt_bytes = (size_t)RT_SHORTS * 2;
  unsigned short* Xp = (unsigned short*)((char*)d_ws + rt_bytes);
  // Xp: NIMG*XROWS*24 shorts (~19.5 MB) + 1 KB slack for the last block's
  // 8 KB LDS stage over-read (staged-but-never-read rows).

  hipMemsetAsync(Rt, 0, rt_bytes, stream);   // zero pad slots of Rt
  hipLaunchKernelGGL(prep_kernel, dim3(64), dim3(256), 0, stream,
                     P_logit, Q, out, Rt);
  int xthreads = NIMG * XROWS * 12;
  hipLaunchKernelGGL(xconv_kernel, dim3((xthreads + 255) / 256), dim3(256),
                     0, stream, X, (unsigned int*)Xp);
  dim3 grid(2, 8, NIMG);   // u-tiles, l-tiles, images
  hipLaunchKernelGGL(conv_kernel, grid, dim3(256), 0, stream, Xp, Rt, out);
}